// Round 1
// baseline (48.594 us; speedup 1.0000x reference)
//
#include <hip/hip_runtime.h>
#include <hip/hip_bf16.h>

typedef short short8 __attribute__((ext_vector_type(8)));
typedef float f32x4 __attribute__((ext_vector_type(4)));

#define CIN   128
#define COUT  128
#define HH    32
#define WW    32
#define NB    32
#define LTOT  1024          // H*W
#define KKT   9
#define KDIM  1152          // KK*CIN
#define BK    32
#define NSTEP 36            // KDIM/BK
#define LDK   40            // padded LDS row length (halfs): 80B stride, 16B aligned

// wt[o*1152 + kk*128 + c] = bf16( w[(o*128+c)*9 + kk] )
__global__ void prep_w_kernel(const float* __restrict__ w, __hip_bfloat16* __restrict__ wt) {
  int i = blockIdx.x * 256 + threadIdx.x;
  if (i >= COUT * KDIM) return;
  int o = i / KDIM;
  int r = i - o * KDIM;
  int kk = r >> 7;
  int c  = r & 127;
  wt[i] = __float2bfloat16(w[(o * CIN + c) * KKT + kk]);
}

// xt[((b*32+h)*32+w)*128 + c] = bf16( x[((b*128+c)*32+h)*32+w] )
__global__ void prep_x_kernel(const float* __restrict__ x, __hip_bfloat16* __restrict__ xt) {
  __shared__ float tile[CIN][WW + 1];     // +1 pad: conflict-free column reads
  int b = blockIdx.x >> 5;
  int h = blockIdx.x & 31;
  const float* src = x + ((size_t)b * CIN * HH + h) * WW;
  for (int i = threadIdx.x; i < CIN * WW; i += 256) {
    int c = i >> 5, w = i & 31;
    tile[c][w] = src[(size_t)c * HH * WW + w];   // coalesced 128B rows
  }
  __syncthreads();
  __hip_bfloat16* dst = xt + ((size_t)(b * HH + h)) * WW * CIN;
  for (int i = threadIdx.x; i < CIN * WW; i += 256) {
    int w = i >> 7, c = i & 127;
    dst[w * CIN + c] = __float2bfloat16(tile[c][w]);   // coalesced bf16 writes
  }
}

// GEMM: D[m=o][n=l_local] = sum_k A[o][k] * B[k][l],  k = kk*128 + c
// block: b = bid>>3, l0 = (bid&7)*128.  512 threads = 8 waves, wave tile 64(o) x 32(l).
__global__ __launch_bounds__(512)
void conv_mfma_kernel(const __hip_bfloat16* __restrict__ wt,
                      const __hip_bfloat16* __restrict__ xt,
                      const float* __restrict__ mask,
                      const float* __restrict__ bias,
                      float* __restrict__ out) {
  __shared__ __hip_bfloat16 Alds[2][COUT][LDK];   // weights  [o][k_local]
  __shared__ __hip_bfloat16 Blds[2][128][LDK];    // patches  [l_local][k_local]

  const int tid = threadIdx.x;
  const int b  = blockIdx.x >> 3;
  const int l0 = (blockIdx.x & 7) << 7;

  // staging: 512 chunks of 16B per tile, one per thread
  const int srow = tid >> 2;     // 0..127 (o row for A, l row for B)
  const int sch  = tid & 3;      // 16B chunk within 64B k-slice

  const int l  = l0 + srow;
  const int hh = l >> 5;
  const int wl_ = l & 31;

  const int lane = tid & 63;
  const int wid  = tid >> 6;
  const int m_base = (wid >> 2) * 64;
  const int n_base = (wid & 3) * 32;
  const int lr = lane & 15;
  const int lg = lane >> 4;

  f32x4 acc[4][2];
  #pragma unroll
  for (int i = 0; i < 4; ++i)
    #pragma unroll
    for (int j = 0; j < 2; ++j)
      acc[i][j] = (f32x4){0.f, 0.f, 0.f, 0.f};

  auto stage_load = [&](int s, uint4& va, uint4& vb, float& mv) {
    va = *(const uint4*)(wt + (size_t)srow * KDIM + s * BK + sch * 8);
    int kk = s >> 2;
    int c0 = (s & 3) * BK;
    int hp = hh + (kk / 3) - 1;
    int wp = wl_ + (kk % 3) - 1;
    if (hp >= 0 && hp < HH && wp >= 0 && wp < WW) {
      vb = *(const uint4*)(xt + ((size_t)((b * HH + hp) * WW + wp)) * CIN + c0 + sch * 8);
    } else {
      vb.x = vb.y = vb.z = vb.w = 0u;
    }
    mv = mask[kk * LTOT + l];
  };

  auto stage_write = [&](int nb, const uint4& va, const uint4& vb, float mv) {
    *(uint4*)&Alds[nb][srow][sch * 8] = va;            // pure copy (already bf16)
    union { uint4 u; unsigned short s[8]; } iv, ov;
    iv.u = vb;
    #pragma unroll
    for (int j = 0; j < 8; ++j) {
      float f = __uint_as_float((unsigned)iv.s[j] << 16) * mv;
      __hip_bfloat16 hb = __float2bfloat16(f);
      ov.s[j] = __builtin_bit_cast(unsigned short, hb);
    }
    *(uint4*)&Blds[nb][srow][sch * 8] = ov.u;
  };

  { // prologue: stage step 0
    uint4 va, vb; float mv;
    stage_load(0, va, vb, mv);
    stage_write(0, va, vb, mv);
  }
  __syncthreads();

  int buf = 0;
  for (int s = 0; s < NSTEP; ++s) {
    uint4 va, vb; float mv = 0.f;
    const bool hn = (s + 1 < NSTEP);
    if (hn) stage_load(s + 1, va, vb, mv);   // issue global loads early (T14)

    short8 af[4], bfr[2];
    #pragma unroll
    for (int mi = 0; mi < 4; ++mi)
      af[mi] = *(const short8*)&Alds[buf][m_base + mi * 16 + lr][lg * 8];
    #pragma unroll
    for (int nj = 0; nj < 2; ++nj)
      bfr[nj] = *(const short8*)&Blds[buf][n_base + nj * 16 + lr][lg * 8];
    #pragma unroll
    for (int mi = 0; mi < 4; ++mi)
      #pragma unroll
      for (int nj = 0; nj < 2; ++nj)
        acc[mi][nj] = __builtin_amdgcn_mfma_f32_16x16x32_bf16(af[mi], bfr[nj], acc[mi][nj], 0, 0, 0);

    if (hn) stage_write(buf ^ 1, va, vb, mv);   // vmcnt wait lands here, after MFMAs
    __syncthreads();
    buf ^= 1;
  }

  // epilogue: C/D layout col=lane&15 (n=l), row=(lane>>4)*4+r (m=o); coalesced over l
  float* outb = out + ((size_t)b * COUT) * LTOT + l0;
  #pragma unroll
  for (int mi = 0; mi < 4; ++mi) {
    #pragma unroll
    for (int r = 0; r < 4; ++r) {
      int o = m_base + mi * 16 + lg * 4 + r;
      float bv = bias[o];
      #pragma unroll
      for (int nj = 0; nj < 2; ++nj) {
        int n = n_base + nj * 16 + lr;
        outb[(size_t)o * LTOT + n] = acc[mi][nj][r] + bv;
      }
    }
  }
}

extern "C" void kernel_launch(void* const* d_in, const int* in_sizes, int n_in,
                              void* d_out, int out_size, void* d_ws, size_t ws_size,
                              hipStream_t stream) {
  const float* x    = (const float*)d_in[0];
  const float* mask = (const float*)d_in[1];
  const float* w    = (const float*)d_in[2];
  const float* bias = (const float*)d_in[3];
  float* out = (float*)d_out;

  __hip_bfloat16* wt = (__hip_bfloat16*)d_ws;                      // 294,912 B
  __hip_bfloat16* xt = (__hip_bfloat16*)((char*)d_ws + 294912);    // 8,388,608 B

  prep_w_kernel<<<(COUT * KDIM + 255) / 256, 256, 0, stream>>>(w, wt);
  prep_x_kernel<<<NB * HH, 256, 0, stream>>>(x, xt);
  conv_mfma_kernel<<<256, 512, 0, stream>>>(wt, xt, mask, bias, out);
}

// Round 2
// 40.327 us; speedup vs baseline: 1.2050x; 1.2050x over previous
//
#include <hip/hip_runtime.h>
#include <hip/hip_bf16.h>

typedef short short8 __attribute__((ext_vector_type(8)));
typedef float f32x4 __attribute__((ext_vector_type(4)));

#define CIN   128
#define COUT  128
#define HH    32
#define WW    32
#define NB    32
#define LTOT  1024
#define KKT   9
#define KDIM  1152
#define BK    64
#define NT    18          // 1152/64 K-tiles
#define BN    64

#define WT_OFF   0
#define WT_BYTES (COUT*KDIM*2)            // 294912
#define XT_OFF   WT_BYTES
#define XT_BYTES (NB*HH*WW*CIN*2)         // 8388608
#define ZP_OFF   (XT_OFF + XT_BYTES)      // 8683520, 16B aligned
#define ZP_BYTES 4096

// ---------------- prep: xt transpose + wt transpose + zero page -------------
__global__ void prep_kernel(const float* __restrict__ x, const float* __restrict__ w,
                            char* __restrict__ ws) {
  int bid = blockIdx.x;
  if (bid < 1024) {
    // xt[((b*32+h)*32+w)*128 + c] = bf16(x[((b*128+c)*32+h)*32+w])
    __shared__ float tile[CIN][WW + 1];
    int b = bid >> 5, h = bid & 31;
    const float* src = x + ((size_t)b * CIN * HH + h) * WW;
    for (int i = threadIdx.x; i < CIN * WW; i += 256) {
      int c = i >> 5, wv = i & 31;
      tile[c][wv] = src[(size_t)c * HH * WW + wv];
    }
    __syncthreads();
    __hip_bfloat16* dst = (__hip_bfloat16*)(ws + XT_OFF) + (size_t)(b * HH + h) * WW * CIN;
    for (int i = threadIdx.x; i < CIN * WW; i += 256) {
      int wv = i >> 7, c = i & 127;
      dst[wv * CIN + c] = __float2bfloat16(tile[c][wv]);
    }
  } else if (bid < 1600) {
    // wt[o*1152 + kk*128 + c] = bf16(w[(o*128+c)*9 + kk])
    int i = (bid - 1024) * 256 + threadIdx.x;    // exactly covers 147456
    int o = i / KDIM;
    int r = i - o * KDIM;
    int kk = r >> 7, c = r & 127;
    ((__hip_bfloat16*)(ws + WT_OFF))[i] = __float2bfloat16(w[(o * CIN + c) * KKT + kk]);
  } else {
    ((uint4*)(ws + ZP_OFF))[threadIdx.x] = (uint4){0, 0, 0, 0};
  }
}

// ---------------- conv as implicit GEMM -------------------------------------
__device__ __forceinline__ void gld16(const char* g, const __hip_bfloat16* l) {
  __builtin_amdgcn_global_load_lds(
      (const __attribute__((address_space(1))) void*)g,
      (__attribute__((address_space(3))) void*)l, 16, 0, 0);
}

// block tile: 128(o) x 64(l), BK=64, 4 waves (2m x 2n), wave tile 64x32.
// LDS[row][chunk] holds global[row][chunk ^ (row&7)]  (16B chunks, 8/row)
__global__ __launch_bounds__(256, 2)
void conv_mfma_kernel(const char* __restrict__ ws,
                      const float* __restrict__ mask,
                      const float* __restrict__ bias,
                      float* __restrict__ out) {
  __shared__ __hip_bfloat16 Alds[2][COUT][BK];   // 2 x 16KB
  __shared__ __hip_bfloat16 Blds[2][BN][BK];     // 2 x 8KB

  const int tid = threadIdx.x;
  int bid = blockIdx.x;
  bid = (bid & 7) * 64 + (bid >> 3);     // XCD swizzle, bijective (512 % 8 == 0)
  const int b  = bid >> 4;
  const int l0 = (bid & 15) << 6;

  const int lane = tid & 63;
  const int wid  = tid >> 6;
  const int lr = lane & 15;
  const int lg = lane >> 4;
  const int m_base = (wid >> 1) * 64;
  const int n_base = (wid & 1) * 32;

  // staging-side constants: thread handles chunk i = r*256+tid; row=i>>3, chunk=i&7
  const int srow = tid >> 3;                   // 0..31
  const int cs   = (tid & 7) ^ (srow & 7);     // inverse-swizzled source chunk
  const int hbase = l0 >> 5;
  const int wcol  = srow;                      // w column for B rows srow, srow+32
  const int zoff  = ZP_OFF + ((tid & 127) << 4);

  // ds_read-side swizzled chunk offsets (halfs): kchunk = ks*4+lg, xor row&7 = lr&7
  const int c0s = (lg ^ (lr & 7)) * 8;
  const int c1s = ((4 + lg) ^ (lr & 7)) * 8;

  f32x4 acc[4][2], par[4][2];
#pragma unroll
  for (int mi = 0; mi < 4; ++mi)
#pragma unroll
    for (int nj = 0; nj < 2; ++nj) {
      acc[mi][nj] = (f32x4){0.f, 0.f, 0.f, 0.f};
      par[mi][nj] = (f32x4){0.f, 0.f, 0.f, 0.f};
    }

  int aoff = WT_OFF + srow * 2304 + cs * 16;   // + r*73728 per A round, +128/tile
  int bo0, bo1;

  auto bgeom = [&](int kk) {
    int di = (kk * 11) >> 5;                   // kk/3 for kk in [0,9]
    int dj = kk - 3 * di;
    int wp  = wcol + dj - 1;
    int hp0 = hbase + di - 1;
    bool vw = (unsigned)wp < (unsigned)WW;
    bo0 = (vw && (unsigned)hp0 < (unsigned)HH)
            ? XT_OFF + ((b * HH + hp0) * WW + wp) * 256 + cs * 16 : zoff;
    bo1 = (vw && (unsigned)(hp0 + 1) < (unsigned)HH)
            ? XT_OFF + ((b * HH + hp0 + 1) * WW + wp) * 256 + cs * 16 : zoff;
  };

  auto stage = [&](int nb) {
    __hip_bfloat16* la = &Alds[nb][0][0] + wid * 512;   // + lane*8 implicit
    __hip_bfloat16* lb = &Blds[nb][0][0] + wid * 512;
    gld16(ws + aoff,          la);
    gld16(ws + aoff + 73728,  la + 2048);
    gld16(ws + aoff + 147456, la + 4096);
    gld16(ws + aoff + 221184, la + 6144);
    gld16(ws + bo0, lb);
    gld16(ws + bo1, lb + 2048);
  };

  bgeom(0);
  stage(0);
  const float* mrow = mask + l0 + n_base + lr;
  float mv0 = 0.f, mv1 = 0.f;
  __syncthreads();

  for (int t = 0; t < NT; ++t) {
    const int buf = t & 1;
    const int kk  = t >> 1;
    if (t < NT - 1) {
      if (t & 1) bgeom(kk + 1);
      else       { bo0 += 128; bo1 += 128; }
      aoff += 128;
      stage(buf ^ 1);                          // async global->LDS for next tile
    }
    if (!(t & 1)) {
      mv0 = mrow[kk * LTOT];
      mv1 = mrow[kk * LTOT + 16];
    }
#pragma unroll
    for (int ks = 0; ks < 2; ++ks) {
      const int cc = ks ? c1s : c0s;
      short8 af0 = *(const short8*)&Alds[buf][m_base      + lr][cc];
      short8 af1 = *(const short8*)&Alds[buf][m_base + 16 + lr][cc];
      short8 af2 = *(const short8*)&Alds[buf][m_base + 32 + lr][cc];
      short8 af3 = *(const short8*)&Alds[buf][m_base + 48 + lr][cc];
      short8 bf0 = *(const short8*)&Blds[buf][n_base      + lr][cc];
      short8 bf1 = *(const short8*)&Blds[buf][n_base + 16 + lr][cc];
      par[0][0] = __builtin_amdgcn_mfma_f32_16x16x32_bf16(af0, bf0, par[0][0], 0, 0, 0);
      par[1][0] = __builtin_amdgcn_mfma_f32_16x16x32_bf16(af1, bf0, par[1][0], 0, 0, 0);
      par[2][0] = __builtin_amdgcn_mfma_f32_16x16x32_bf16(af2, bf0, par[2][0], 0, 0, 0);
      par[3][0] = __builtin_amdgcn_mfma_f32_16x16x32_bf16(af3, bf0, par[3][0], 0, 0, 0);
      par[0][1] = __builtin_amdgcn_mfma_f32_16x16x32_bf16(af0, bf1, par[0][1], 0, 0, 0);
      par[1][1] = __builtin_amdgcn_mfma_f32_16x16x32_bf16(af1, bf1, par[1][1], 0, 0, 0);
      par[2][1] = __builtin_amdgcn_mfma_f32_16x16x32_bf16(af2, bf1, par[2][1], 0, 0, 0);
      par[3][1] = __builtin_amdgcn_mfma_f32_16x16x32_bf16(af3, bf1, par[3][1], 0, 0, 0);
    }
    if (t & 1) {                                // end of kk: mask-fold into acc
#pragma unroll
      for (int mi = 0; mi < 4; ++mi)
#pragma unroll
        for (int r = 0; r < 4; ++r) {
          acc[mi][0][r] += mv0 * par[mi][0][r];
          acc[mi][1][r] += mv1 * par[mi][1][r];
          par[mi][0][r] = 0.f;
          par[mi][1][r] = 0.f;
        }
    }
    __syncthreads();
  }

  // epilogue: C/D layout col(l)=lane&15, row(o)=(lane>>4)*4+r
  float* outb = out + ((size_t)b * COUT) * LTOT + l0;
#pragma unroll
  for (int mi = 0; mi < 4; ++mi) {
#pragma unroll
    for (int r = 0; r < 4; ++r) {
      int o = m_base + mi * 16 + lg * 4 + r;
      float bv = bias[o];
      outb[(size_t)o * LTOT + n_base      + lr] = acc[mi][0][r] + bv;
      outb[(size_t)o * LTOT + n_base + 16 + lr] = acc[mi][1][r] + bv;
    }
  }
}

extern "C" void kernel_launch(void* const* d_in, const int* in_sizes, int n_in,
                              void* d_out, int out_size, void* d_ws, size_t ws_size,
                              hipStream_t stream) {
  const float* x    = (const float*)d_in[0];
  const float* mask = (const float*)d_in[1];
  const float* w    = (const float*)d_in[2];
  const float* bias = (const float*)d_in[3];
  float* out = (float*)d_out;
  char* ws = (char*)d_ws;

  prep_kernel<<<1601, 256, 0, stream>>>(x, w, ws);
  conv_mfma_kernel<<<512, 256, 0, stream>>>(ws, mask, bias, out);
}